// Round 3
// baseline (1012.249 us; speedup 1.0000x reference)
//
#include <hip/hip_runtime.h>
#include <math.h>

#define D 256
#define NSEG 8192
#define G 2   // segments per block; G=2 keeps pass1->pass2 reuse footprint under LLC (256 MB)

// Kernel A: segment boundaries from the sorted index. starts[s] = first i with obj[i] >= s.
// Covers empty segments (gap fill) and the tail; writes all N+1 entries every call
// (d_ws is re-poisoned before every launch).
__global__ __launch_bounds__(256) void boundaries_kernel(const int* __restrict__ obj, int T,
                                                         int* __restrict__ starts) {
    const int i = blockIdx.x * 256 + threadIdx.x;
    if (i >= T) return;
    const int v = obj[i];
    const int p = (i == 0) ? -1 : obj[i - 1];
    for (int s = p + 1; s <= v; ++s) starts[s] = i;
    if (i == T - 1) {
        for (int s = v + 1; s <= NSEG; ++s) starts[s] = T;
    }
}

// Kernel B: fully fused, G segments per block (256 threads = 4 waves).
//   pass 1: per-segment sum (HBM read, coalesced float4)
//   proj  : tg = tanh((s @ W)/cnt) -- W read once per G segments (L2-hot)
//   pass 2: re-read rows (LLC-hot), score = sigmoid(row.tg), rep += row*score,
//           broadcast rep to all rows of the segment.
__global__ __launch_bounds__(256) void fused_seg_kernel(
        const float* __restrict__ emb,
        const float* __restrict__ W,
        const int*   __restrict__ starts,
        float* __restrict__ out) {
    const int seg0 = blockIdx.x * G;
    const int tid  = threadIdx.x;
    const int lane = tid & 63;
    const int w    = tid >> 6;

    __shared__ float sv[G][D];   // segment sums
    __shared__ float tg[G][D];   // contexts
    __shared__ float sm[4][D];   // cross-wave reduction scratch
    __shared__ int   bnd[G + 1];

    if (tid <= G) bnd[tid] = starts[seg0 + tid];
    __syncthreads();

    // ---- pass 1: segment sums ----
    for (int g = 0; g < G; ++g) {
        const int s0 = bnd[g], s1 = bnd[g + 1];
        float4 acc = make_float4(0.f, 0.f, 0.f, 0.f);
        #pragma unroll 2
        for (int r = s0 + w; r < s1; r += 4) {
            const float4 e = *reinterpret_cast<const float4*>(emb + (size_t)r * D + lane * 4);
            acc.x += e.x; acc.y += e.y; acc.z += e.z; acc.w += e.w;
        }
        *reinterpret_cast<float4*>(&sm[w][lane * 4]) = acc;
        __syncthreads();
        sv[g][tid] = sm[0][tid] + sm[1][tid] + sm[2][tid] + sm[3][tid];
        __syncthreads();   // also protects sm before next g reuses it
    }

    // ---- proj: thread tid owns column tid of W; G FMAs per W load ----
    float acc[G];
    #pragma unroll
    for (int g = 0; g < G; ++g) acc[g] = 0.f;
    #pragma unroll 4
    for (int k = 0; k < D; ++k) {
        const float wk = W[k * D + tid];
        #pragma unroll
        for (int g = 0; g < G; ++g) acc[g] += sv[g][k] * wk;
    }
    #pragma unroll
    for (int g = 0; g < G; ++g) {
        const int cnt = bnd[g + 1] - bnd[g];
        tg[g][tid] = tanhf(acc[g] / (float)(cnt > 1 ? cnt : 1));
    }
    __syncthreads();

    // ---- pass 2: score + weighted sum + broadcast ----
    for (int g = 0; g < G; ++g) {
        const int s0 = bnd[g], s1 = bnd[g + 1];
        if (s0 >= s1) { __syncthreads(); continue; }   // keep barriers block-uniform
        const float4 tg4 = *reinterpret_cast<const float4*>(&tg[g][lane * 4]);
        float4 racc = make_float4(0.f, 0.f, 0.f, 0.f);
        #pragma unroll 2
        for (int r = s0 + w; r < s1; r += 4) {
            const float4 e = *reinterpret_cast<const float4*>(emb + (size_t)r * D + lane * 4);
            float pd = e.x * tg4.x + e.y * tg4.y + e.z * tg4.z + e.w * tg4.w;
            #pragma unroll
            for (int off = 32; off >= 1; off >>= 1) pd += __shfl_xor(pd, off, 64);
            const float score = 1.0f / (1.0f + __expf(-pd));
            racc.x += e.x * score; racc.y += e.y * score;
            racc.z += e.z * score; racc.w += e.w * score;
        }
        *reinterpret_cast<float4*>(&sm[w][lane * 4]) = racc;
        __syncthreads();
        sm[0][tid] = sm[0][tid] + sm[1][tid] + sm[2][tid] + sm[3][tid];
        __syncthreads();
        const float4 rep4 = *reinterpret_cast<const float4*>(&sm[0][lane * 4]);
        for (int r = s0 + w; r < s1; r += 4) {
            *reinterpret_cast<float4*>(out + (size_t)r * D + lane * 4) = rep4;
        }
        __syncthreads();   // rep4 consumed; sm safe to reuse next g
    }
}

extern "C" void kernel_launch(void* const* d_in, const int* in_sizes, int n_in,
                              void* d_out, int out_size, void* d_ws, size_t ws_size,
                              hipStream_t stream) {
    const float* emb = (const float*)d_in[0];
    const float* W   = (const float*)d_in[1];
    const int*   obj = (const int*)d_in[2];
    const int T = in_sizes[2];
    float* out = (float*)d_out;

    int* starts = (int*)d_ws;   // NSEG+1 ints

    boundaries_kernel<<<(T + 255) / 256, 256, 0, stream>>>(obj, T, starts);
    fused_seg_kernel<<<NSEG / G, 256, 0, stream>>>(emb, W, starts, out);
}